// Round 2
// baseline (282.785 us; speedup 1.0000x reference)
//
#include <hip/hip_runtime.h>
#include <math.h>

#define NN 864
#define INF_ 4096
#define OUTF 1024
#define ALPHA 0.2f
#define NEGINF -9e15f

#define BM 128
#define BN 64
#define BK 16
#define LDA_ 132   // BM + 4 pad: transpose-writes 2-way (free), reads 16B-aligned
#define KSPLIT1 4
#define KSPLIT2 3

// ---------- block-wide reduction of two values (256 threads = 4 waves) ----------
__device__ __forceinline__ float2 blockReduce2(float v1, float v2, bool is_max) {
    __shared__ float r1[4], r2[4];
    const int lane = threadIdx.x & 63;
    const int wid  = threadIdx.x >> 6;
#pragma unroll
    for (int o = 32; o; o >>= 1) {
        float o1 = __shfl_down(v1, o, 64);
        float o2 = __shfl_down(v2, o, 64);
        if (is_max) { v1 = fmaxf(v1, o1); v2 = fmaxf(v2, o2); }
        else        { v1 += o1;           v2 += o2; }
    }
    __syncthreads();                 // protect smem reuse across calls
    if (lane == 0) { r1[wid] = v1; r2[wid] = v2; }
    __syncthreads();
    float a = r1[0], b = r2[0];
#pragma unroll
    for (int w = 1; w < 4; ++w) {
        if (is_max) { a = fmaxf(a, r1[w]); b = fmaxf(b, r2[w]); }
        else        { a += r1[w];          b += r2[w]; }
    }
    return make_float2(a, b);
}

// ---------- shared GEMM: P[ks] = Acomb[:, k0:k1] @ B[k0:k1, :] ----------
// Acomb = A when A2==null, else w0*A + w1*A2 (weights from wvec).
// 128x64 tile, 8x4 micro-tile, A staged k-major (transposed) in LDS.
__global__ __launch_bounds__(256) void gemm_kernel(
        const float* __restrict__ A, const float* __restrict__ A2,
        const float* __restrict__ wvec, const float* __restrict__ B,
        float* __restrict__ P, int M, int N, int K, int kchunk) {
    __shared__ __align__(16) float As[BK][LDA_];
    __shared__ __align__(16) float Bs[BK][BN];
    const int tid  = threadIdx.x;
    const int brow = blockIdx.y * BM;
    const int bcol = blockIdx.x * BN;
    const int k0   = blockIdx.z * kchunk;
    const int ar = tid >> 2;               // 0..63 (row within half-tile)
    const int ak = (tid & 3) << 2;         // k offset 0,4,8,12
    const int bk = tid >> 4;               // 0..15
    const int bn = (tid & 15) << 2;        // 0..60
    const int ty = tid >> 4;               // 0..15 -> 8 rows each
    const int tx = tid & 15;               // 0..15 -> 4 cols each
    float w0 = 1.f, w1 = 0.f;
    if (wvec) { w0 = wvec[0]; w1 = wvec[1]; }
    float acc[8][4] = {};
    for (int kk = k0; kk < k0 + kchunk; kk += BK) {
#pragma unroll
        for (int half = 0; half < 2; ++half) {
            const int r = ar + half * 64;
            const int grow = brow + r;
            float4 av = make_float4(0.f, 0.f, 0.f, 0.f);
            if (grow < M) {
                av = *(const float4*)(A + (size_t)grow * K + kk + ak);
                if (A2) {
                    float4 v2 = *(const float4*)(A2 + (size_t)grow * K + kk + ak);
                    av.x = w0 * av.x + w1 * v2.x;
                    av.y = w0 * av.y + w1 * v2.y;
                    av.z = w0 * av.z + w1 * v2.z;
                    av.w = w0 * av.w + w1 * v2.w;
                }
            }
            As[ak + 0][r] = av.x;          // transpose into k-major
            As[ak + 1][r] = av.y;
            As[ak + 2][r] = av.z;
            As[ak + 3][r] = av.w;
        }
        *(float4*)&Bs[bk][bn] = *(const float4*)(B + (size_t)(kk + bk) * N + bcol + bn);
        __syncthreads();
#pragma unroll
        for (int k = 0; k < BK; ++k) {
            float4 a0 = *(float4*)&As[k][ty * 8];
            float4 a1 = *(float4*)&As[k][ty * 8 + 4];
            float4 b  = *(float4*)&Bs[k][tx << 2];
            acc[0][0] += a0.x * b.x; acc[0][1] += a0.x * b.y; acc[0][2] += a0.x * b.z; acc[0][3] += a0.x * b.w;
            acc[1][0] += a0.y * b.x; acc[1][1] += a0.y * b.y; acc[1][2] += a0.y * b.z; acc[1][3] += a0.y * b.w;
            acc[2][0] += a0.z * b.x; acc[2][1] += a0.z * b.y; acc[2][2] += a0.z * b.z; acc[2][3] += a0.z * b.w;
            acc[3][0] += a0.w * b.x; acc[3][1] += a0.w * b.y; acc[3][2] += a0.w * b.z; acc[3][3] += a0.w * b.w;
            acc[4][0] += a1.x * b.x; acc[4][1] += a1.x * b.y; acc[4][2] += a1.x * b.z; acc[4][3] += a1.x * b.w;
            acc[5][0] += a1.y * b.x; acc[5][1] += a1.y * b.y; acc[5][2] += a1.y * b.z; acc[5][3] += a1.y * b.w;
            acc[6][0] += a1.z * b.x; acc[6][1] += a1.z * b.y; acc[6][2] += a1.z * b.z; acc[6][3] += a1.z * b.w;
            acc[7][0] += a1.w * b.x; acc[7][1] += a1.w * b.y; acc[7][2] += a1.w * b.z; acc[7][3] += a1.w * b.w;
        }
        __syncthreads();
    }
    float* Pout = P + (size_t)blockIdx.z * M * N;
#pragma unroll
    for (int ii = 0; ii < 8; ++ii) {
        const int row = brow + ty * 8 + ii;
        if (row < M)
            *(float4*)(Pout + (size_t)row * N + bcol + (tx << 2)) =
                make_float4(acc[ii][0], acc[ii][1], acc[ii][2], acc[ii][3]);
    }
}

// ---------- reduce 4 split-K partials -> Wh ----------
__global__ __launch_bounds__(256) void reduce4_kernel(const float* __restrict__ P,
                                                      float* __restrict__ Wh) {
    const size_t stride = (size_t)NN * OUTF;
    size_t idx = ((size_t)blockIdx.x * 256 + threadIdx.x) * 4;
    float4 v0 = *(const float4*)(P + idx);
    float4 v1 = *(const float4*)(P + stride + idx);
    float4 v2 = *(const float4*)(P + 2 * stride + idx);
    float4 v3 = *(const float4*)(P + 3 * stride + idx);
    float4 r = make_float4(v0.x + v1.x + v2.x + v3.x, v0.y + v1.y + v2.y + v3.y,
                           v0.z + v1.z + v2.z + v3.z, v0.w + v1.w + v2.w + v3.w);
    *(float4*)(Wh + idx) = r;
}

// ---------- Wh1 = Wh@a1, Wh2 = Wh@a2 (one block per row) ----------
__global__ __launch_bounds__(256) void proj_kernel(const float* __restrict__ Wh,
                                                   const float* __restrict__ a,
                                                   float* __restrict__ Wh1,
                                                   float* __restrict__ Wh2) {
    const int i = blockIdx.x;
    const float* row = Wh + (size_t)i * OUTF;
    const int f = threadIdx.x << 2;  // 256 threads * 4 = 1024 exactly
    float4 w  = *(const float4*)(row + f);
    float4 a1 = *(const float4*)(a + f);
    float4 a2 = *(const float4*)(a + OUTF + f);
    float s1 = w.x * a1.x + w.y * a1.y + w.z * a1.z + w.w * a1.w;
    float s2 = w.x * a2.x + w.y * a2.y + w.z * a2.z + w.w * a2.w;
    float2 s = blockReduce2(s1, s2, false);
    if (threadIdx.x == 0) { Wh1[i] = s.x; Wh2[i] = s.y; }
}

// ---------- attention: e=leaky(Wh1_i+Wh2_j), two masked softmaxes (block per row) ----------
__global__ __launch_bounds__(256) void attn_kernel(
        const float* __restrict__ Wh1, const float* __restrict__ Wh2,
        const int* __restrict__ adj1, const int* __restrict__ adj2,
        float* __restrict__ att1, float* __restrict__ att2) {
    const int i   = blockIdx.x;
    const int tid = threadIdx.x;
    const float wh1 = Wh1[i];
    float m1 = NEGINF, m2 = NEGINF;
    float l1v[4], l2v[4];
    int cnt = 0;
    for (int j = tid; j < NN; j += 256, ++cnt) {
        float e = wh1 + Wh2[j];
        e = e > 0.f ? e : ALPHA * e;
        float l1 = adj1[(size_t)i * NN + j] > 0 ? e : NEGINF;
        float l2 = adj2[(size_t)i * NN + j] > 0 ? e : NEGINF;
        l1v[cnt] = l1; l2v[cnt] = l2;
        m1 = fmaxf(m1, l1); m2 = fmaxf(m2, l2);
    }
    float2 m = blockReduce2(m1, m2, true);
    float s1 = 0.f, s2 = 0.f;
    float x1v[4], x2v[4];
    cnt = 0;
    for (int j = tid; j < NN; j += 256, ++cnt) {
        float x1 = expf(l1v[cnt] - m.x);   // masked & max finite -> underflow to 0, matches JAX
        float x2 = expf(l2v[cnt] - m.y);
        x1v[cnt] = x1; x2v[cnt] = x2;
        s1 += x1; s2 += x2;
    }
    float2 s = blockReduce2(s1, s2, false);
    cnt = 0;
    for (int j = tid; j < NN; j += 256, ++cnt) {
        att1[(size_t)i * NN + j] = x1v[cnt] / s.x;
        att2[(size_t)i * NN + j] = x2v[cnt] / s.y;
    }
}

// ---------- 16x16 maxpool (one block per output cell) ----------
__global__ __launch_bounds__(256) void pool_kernel(const float* __restrict__ att1,
                                                   const float* __restrict__ att2,
                                                   float* __restrict__ pooled) {
    const int pj = blockIdx.x, pi = blockIdx.y, mIdx = blockIdx.z;
    const float* att = mIdx ? att2 : att1;
    const int ty = threadIdx.x >> 4, tx = threadIdx.x & 15;
    float v = att[(size_t)(pi * 16 + ty) * NN + pj * 16 + tx];
    float2 r = blockReduce2(v, v, true);
    if (threadIdx.x == 0) pooled[mIdx * 2916 + pi * 54 + pj] = r.x;
}

// ---------- pooled -> linear -> leaky -> softmax over 2 maps ----------
__global__ __launch_bounds__(256) void weights_kernel(const float* __restrict__ pooled,
                                                      const float* __restrict__ L_w,
                                                      const float* __restrict__ L_b,
                                                      float* __restrict__ wvec) {
    float p0 = 0.f, p1 = 0.f;
    for (int p = threadIdx.x; p < 2916; p += 256) {
        float lw = L_w[p];
        p0 += pooled[p] * lw;
        p1 += pooled[2916 + p] * lw;
    }
    float2 s = blockReduce2(p0, p1, false);
    if (threadIdx.x == 0) {
        float l0 = s.x + L_b[0]; l0 = l0 > 0.f ? l0 : ALPHA * l0;
        float l1 = s.y + L_b[0]; l1 = l1 > 0.f ? l1 : ALPHA * l1;
        float mx = fmaxf(l0, l1);
        float e0 = expf(l0 - mx), e1 = expf(l1 - mx);
        float inv = 1.f / (e0 + e1);
        wvec[0] = e0 * inv; wvec[1] = e1 * inv;
    }
}

// ---------- reduce 3 split-K partials + ELU -> out ----------
__global__ __launch_bounds__(256) void reduce3_elu_kernel(const float* __restrict__ P,
                                                          float* __restrict__ out) {
    const size_t stride = (size_t)NN * OUTF;
    size_t idx = ((size_t)blockIdx.x * 256 + threadIdx.x) * 4;
    float4 v0 = *(const float4*)(P + idx);
    float4 v1 = *(const float4*)(P + stride + idx);
    float4 v2 = *(const float4*)(P + 2 * stride + idx);
    float r[4];
    r[0] = v0.x + v1.x + v2.x; r[1] = v0.y + v1.y + v2.y;
    r[2] = v0.z + v1.z + v2.z; r[3] = v0.w + v1.w + v2.w;
#pragma unroll
    for (int k = 0; k < 4; ++k) r[k] = r[k] > 0.f ? r[k] : expm1f(r[k]);
    *(float4*)(out + idx) = make_float4(r[0], r[1], r[2], r[3]);
}

extern "C" void kernel_launch(void* const* d_in, const int* in_sizes, int n_in,
                              void* d_out, int out_size, void* d_ws, size_t ws_size,
                              hipStream_t stream) {
    const float* h    = (const float*)d_in[0];
    // d_in[1] = adj (unused by the reference computation)
    const int*   adj1 = (const int*)d_in[2];
    const int*   adj2 = (const int*)d_in[3];
    const float* W    = (const float*)d_in[4];
    const float* a    = (const float*)d_in[5];
    const float* L_w  = (const float*)d_in[6];
    const float* L_b  = (const float*)d_in[7];
    float* out = (float*)d_out;

    float* ws     = (float*)d_ws;
    float* P      = ws;                              // 4 * 884736 (reused by gemm2: 3 slices)
    float* Wh     = P + 4 * (size_t)NN * OUTF;       // 884736
    float* att1   = Wh + (size_t)NN * OUTF;          // 746496
    float* att2   = att1 + (size_t)NN * NN;          // 746496
    float* Wh1    = att2 + (size_t)NN * NN;          // 864
    float* Wh2    = Wh1 + NN;                        // 864
    float* pooled = Wh2 + NN;                        // 5832
    float* wvec   = pooled + 5832;                   // 2

    dim3 g1(OUTF / BN, (NN + BM - 1) / BM, KSPLIT1); // (16,7,4)
    gemm_kernel<<<g1, 256, 0, stream>>>(h, nullptr, nullptr, W, P,
                                        NN, OUTF, INF_, INF_ / KSPLIT1);
    reduce4_kernel<<<NN, 256, 0, stream>>>(P, Wh);
    proj_kernel<<<NN, 256, 0, stream>>>(Wh, a, Wh1, Wh2);
    attn_kernel<<<NN, 256, 0, stream>>>(Wh1, Wh2, adj1, adj2, att1, att2);
    pool_kernel<<<dim3(54, 54, 2), 256, 0, stream>>>(att1, att2, pooled);
    weights_kernel<<<1, 256, 0, stream>>>(pooled, L_w, L_b, wvec);
    dim3 g2(OUTF / BN, (NN + BM - 1) / BM, KSPLIT2); // (16,7,3)
    gemm_kernel<<<g2, 256, 0, stream>>>(att1, att2, wvec, Wh, P,
                                        NN, OUTF, NN, NN / KSPLIT2);
    reduce3_elu_kernel<<<NN, 256, 0, stream>>>(P, out);
}

// Round 3
// 181.759 us; speedup vs baseline: 1.5558x; 1.5558x over previous
//
#include <hip/hip_runtime.h>
#include <math.h>

#define NN 864
#define INF_ 4096
#define OUTF 1024
#define ALPHA 0.2f
#define NEGINF -9e15f

// fp32 GEMM2 tiling
#define BM 128
#define BN 64
#define BK 16
#define LDA_ 132
#define KSPLIT2 9

// bf16 MFMA GEMM1 tiling
#define KSPLIT1 8

typedef short bf16x8 __attribute__((ext_vector_type(8)));
typedef float f32x4 __attribute__((ext_vector_type(4)));
typedef unsigned short u16x8 __attribute__((ext_vector_type(8)));

__device__ __forceinline__ unsigned short f2bf(float f) {  // round-to-nearest-even
    unsigned int u = __float_as_uint(f);
    unsigned int r = (u + 0x7fffu + ((u >> 16) & 1u)) >> 16;
    return (unsigned short)r;
}

// ---------- block-wide reduction of two values (256 threads = 4 waves) ----------
__device__ __forceinline__ float2 blockReduce2(float v1, float v2, bool is_max) {
    __shared__ float r1[4], r2[4];
    const int lane = threadIdx.x & 63;
    const int wid  = threadIdx.x >> 6;
#pragma unroll
    for (int o = 32; o; o >>= 1) {
        float o1 = __shfl_down(v1, o, 64);
        float o2 = __shfl_down(v2, o, 64);
        if (is_max) { v1 = fmaxf(v1, o1); v2 = fmaxf(v2, o2); }
        else        { v1 += o1;           v2 += o2; }
    }
    __syncthreads();
    if (lane == 0) { r1[wid] = v1; r2[wid] = v2; }
    __syncthreads();
    float a = r1[0], b = r2[0];
#pragma unroll
    for (int w = 1; w < 4; ++w) {
        if (is_max) { a = fmaxf(a, r1[w]); b = fmaxf(b, r2[w]); }
        else        { a += r1[w];          b += r2[w]; }
    }
    return make_float2(a, b);
}

// ---------- h fp32 [864][4096] -> bf16 [896][4096], zero-padded tail rows ----------
__global__ __launch_bounds__(256) void convert_h_kernel(const float* __restrict__ h,
                                                        unsigned short* __restrict__ hbf) {
    const int i = blockIdx.x * 256 + threadIdx.x;     // 458752 threads, 8 elems each
    const size_t base = (size_t)i * 8;
    const int row = (int)(base >> 12);
    u16x8 o;
    if (row < NN) {
        float4 f0 = *(const float4*)(h + base);
        float4 f1 = *(const float4*)(h + base + 4);
        o[0] = f2bf(f0.x); o[1] = f2bf(f0.y); o[2] = f2bf(f0.z); o[3] = f2bf(f0.w);
        o[4] = f2bf(f1.x); o[5] = f2bf(f1.y); o[6] = f2bf(f1.z); o[7] = f2bf(f1.w);
    } else {
#pragma unroll
        for (int j = 0; j < 8; ++j) o[j] = 0;
    }
    *(u16x8*)(hbf + base) = o;
}

// ---------- W fp32 [4096][1024] -> Wt bf16 [1024][4096] (transposed) ----------
__global__ __launch_bounds__(256) void transpose_w_kernel(const float* __restrict__ W,
                                                          unsigned short* __restrict__ wt) {
    const int n  = blockIdx.x * 256 + threadIdx.x;    // 0..1023
    const int k0 = blockIdx.y * 8;                    // 0..4088
    u16x8 o;
#pragma unroll
    for (int j = 0; j < 8; ++j) o[j] = f2bf(W[(size_t)(k0 + j) * OUTF + n]);
    *(u16x8*)(wt + (size_t)n * INF_ + k0) = o;
}

// ---------- Wa1 = W@a[:1024], Wa2 = W@a[1024:]  (fp32 exact path for logits) ----------
__global__ __launch_bounds__(256) void wa_kernel(const float* __restrict__ W,
                                                 const float* __restrict__ a,
                                                 float* __restrict__ wa1,
                                                 float* __restrict__ wa2) {
    const int k = blockIdx.x;
    const float* row = W + (size_t)k * OUTF;
    const int f = threadIdx.x << 2;
    float4 w = *(const float4*)(row + f);
    float4 x = *(const float4*)(a + f);
    float4 y = *(const float4*)(a + OUTF + f);
    float s1 = w.x * x.x + w.y * x.y + w.z * x.z + w.w * x.w;
    float s2 = w.x * y.x + w.y * y.y + w.z * y.z + w.w * y.w;
    float2 s = blockReduce2(s1, s2, false);
    if (threadIdx.x == 0) { wa1[k] = s.x; wa2[k] = s.y; }
}

// ---------- Wh1 = h@Wa1, Wh2 = h@Wa2 (fp32, one block per row) ----------
__global__ __launch_bounds__(256) void wh12_kernel(const float* __restrict__ h,
                                                   const float* __restrict__ wa1,
                                                   const float* __restrict__ wa2,
                                                   float* __restrict__ wh1,
                                                   float* __restrict__ wh2) {
    const int i = blockIdx.x;
    const float* row = h + (size_t)i * INF_;
    float s1 = 0.f, s2 = 0.f;
    for (int f = threadIdx.x << 2; f < INF_; f += 1024) {
        float4 hv = *(const float4*)(row + f);
        float4 x  = *(const float4*)(wa1 + f);
        float4 y  = *(const float4*)(wa2 + f);
        s1 += hv.x * x.x + hv.y * x.y + hv.z * x.z + hv.w * x.w;
        s2 += hv.x * y.x + hv.y * y.y + hv.z * y.z + hv.w * y.w;
    }
    float2 s = blockReduce2(s1, s2, false);
    if (threadIdx.x == 0) { wh1[i] = s.x; wh2[i] = s.y; }
}

// ---------- GEMM1 (bf16 MFMA): P[z] = hbf @ Wt^T, 128x128 tile, BK=32 ----------
__global__ __launch_bounds__(256) void gemm1_mfma_kernel(
        const unsigned short* __restrict__ Abf,   // [896][4096] row-major
        const unsigned short* __restrict__ Btbf,  // [1024][4096] (= W^T) row-major
        float* __restrict__ P, int kchunk) {
    __shared__ unsigned short Als[128][40];   // 80B rows: 16B-aligned b128, ~2-way banks
    __shared__ unsigned short Bls[128][40];
    const int tid  = threadIdx.x;
    const int lane = tid & 63;
    const int wid  = tid >> 6;
    const int wr   = (wid >> 1) * 64;         // wave sub-tile origin (rows)
    const int wc   = (wid & 1) * 64;          // (cols)
    const int brow = blockIdx.y * 128;
    const int bcol = blockIdx.x * 128;
    const int k0   = blockIdx.z * kchunk;
    const int r0   = tid >> 2;                // 0..63 (staging row; +64 for second chunk)
    const int kq0  = (tid & 3) << 3;          // 0,8,16,24

    f32x4 acc[4][4];
#pragma unroll
    for (int m = 0; m < 4; ++m)
#pragma unroll
        for (int n = 0; n < 4; ++n) acc[m][n] = (f32x4){0.f, 0.f, 0.f, 0.f};

    const unsigned short* ag = Abf  + (size_t)(brow + r0) * INF_ + kq0;
    const unsigned short* bg = Btbf + (size_t)(bcol + r0) * INF_ + kq0;
    const int rl  = lane & 15;
    const int kq2 = (lane >> 4) << 3;

    for (int kk = k0; kk < k0 + kchunk; kk += 32) {
        bf16x8 a0 = *(const bf16x8*)(ag + kk);
        bf16x8 a1 = *(const bf16x8*)(ag + (size_t)64 * INF_ + kk);
        bf16x8 b0 = *(const bf16x8*)(bg + kk);
        bf16x8 b1 = *(const bf16x8*)(bg + (size_t)64 * INF_ + kk);
        __syncthreads();                       // previous iter's ds_reads done
        *(bf16x8*)&Als[r0][kq0]      = a0;
        *(bf16x8*)&Als[r0 + 64][kq0] = a1;
        *(bf16x8*)&Bls[r0][kq0]      = b0;
        *(bf16x8*)&Bls[r0 + 64][kq0] = b1;
        __syncthreads();
        bf16x8 af[4], bfr[4];
#pragma unroll
        for (int m = 0; m < 4; ++m) af[m]  = *(const bf16x8*)&Als[wr + m * 16 + rl][kq2];
#pragma unroll
        for (int n = 0; n < 4; ++n) bfr[n] = *(const bf16x8*)&Bls[wc + n * 16 + rl][kq2];
#pragma unroll
        for (int m = 0; m < 4; ++m)
#pragma unroll
            for (int n = 0; n < 4; ++n)
                acc[m][n] = __builtin_amdgcn_mfma_f32_16x16x32_bf16(af[m], bfr[n], acc[m][n], 0, 0, 0);
    }

    float* Pz = P + (size_t)blockIdx.z * NN * OUTF;
    const int rg = (lane >> 4) << 2;          // C/D: col=lane&15, row=(lane>>4)*4+reg (m89)
#pragma unroll
    for (int m = 0; m < 4; ++m) {
#pragma unroll
        for (int n = 0; n < 4; ++n) {
            const int row0 = brow + wr + m * 16 + rg;
            const int col  = bcol + wc + n * 16 + rl;
#pragma unroll
            for (int reg = 0; reg < 4; ++reg) {
                const int row = row0 + reg;
                if (row < NN) Pz[(size_t)row * OUTF + col] = acc[m][n][reg];
            }
        }
    }
}

// ---------- reduce 8 split-K partials -> Wh ----------
__global__ __launch_bounds__(256) void reduce8_kernel(const float* __restrict__ P,
                                                      float* __restrict__ Wh) {
    const size_t stride = (size_t)NN * OUTF;
    size_t idx = ((size_t)blockIdx.x * 256 + threadIdx.x) * 4;
    float4 r = *(const float4*)(P + idx);
#pragma unroll
    for (int z = 1; z < KSPLIT1; ++z) {
        float4 v = *(const float4*)(P + z * stride + idx);
        r.x += v.x; r.y += v.y; r.z += v.z; r.w += v.w;
    }
    *(float4*)(Wh + idx) = r;
}

// ---------- attention: e=leaky(Wh1_i+Wh2_j), two masked softmaxes (block per row) ----------
__global__ __launch_bounds__(256) void attn_kernel(
        const float* __restrict__ Wh1, const float* __restrict__ Wh2,
        const int* __restrict__ adj1, const int* __restrict__ adj2,
        float* __restrict__ att1, float* __restrict__ att2) {
    const int i   = blockIdx.x;
    const int tid = threadIdx.x;
    const float wh1 = Wh1[i];
    float m1 = NEGINF, m2 = NEGINF;
    float l1v[4], l2v[4];
    int cnt = 0;
    for (int j = tid; j < NN; j += 256, ++cnt) {
        float e = wh1 + Wh2[j];
        e = e > 0.f ? e : ALPHA * e;
        float l1 = adj1[(size_t)i * NN + j] > 0 ? e : NEGINF;
        float l2 = adj2[(size_t)i * NN + j] > 0 ? e : NEGINF;
        l1v[cnt] = l1; l2v[cnt] = l2;
        m1 = fmaxf(m1, l1); m2 = fmaxf(m2, l2);
    }
    float2 m = blockReduce2(m1, m2, true);
    float s1 = 0.f, s2 = 0.f;
    float x1v[4], x2v[4];
    cnt = 0;
    for (int j = tid; j < NN; j += 256, ++cnt) {
        float x1 = expf(l1v[cnt] - m.x);
        float x2 = expf(l2v[cnt] - m.y);
        x1v[cnt] = x1; x2v[cnt] = x2;
        s1 += x1; s2 += x2;
    }
    float2 s = blockReduce2(s1, s2, false);
    cnt = 0;
    for (int j = tid; j < NN; j += 256, ++cnt) {
        att1[(size_t)i * NN + j] = x1v[cnt] / s.x;
        att2[(size_t)i * NN + j] = x2v[cnt] / s.y;
    }
}

// ---------- 16x16 maxpool (one block per output cell) ----------
__global__ __launch_bounds__(256) void pool_kernel(const float* __restrict__ att1,
                                                   const float* __restrict__ att2,
                                                   float* __restrict__ pooled) {
    const int pj = blockIdx.x, pi = blockIdx.y, mIdx = blockIdx.z;
    const float* att = mIdx ? att2 : att1;
    const int ty = threadIdx.x >> 4, tx = threadIdx.x & 15;
    float v = att[(size_t)(pi * 16 + ty) * NN + pj * 16 + tx];
    float2 r = blockReduce2(v, v, true);
    if (threadIdx.x == 0) pooled[mIdx * 2916 + pi * 54 + pj] = r.x;
}

// ---------- pooled -> linear -> leaky -> softmax over 2 maps ----------
__global__ __launch_bounds__(256) void weights_kernel(const float* __restrict__ pooled,
                                                      const float* __restrict__ L_w,
                                                      const float* __restrict__ L_b,
                                                      float* __restrict__ wvec) {
    float p0 = 0.f, p1 = 0.f;
    for (int p = threadIdx.x; p < 2916; p += 256) {
        float lw = L_w[p];
        p0 += pooled[p] * lw;
        p1 += pooled[2916 + p] * lw;
    }
    float2 s = blockReduce2(p0, p1, false);
    if (threadIdx.x == 0) {
        float l0 = s.x + L_b[0]; l0 = l0 > 0.f ? l0 : ALPHA * l0;
        float l1 = s.y + L_b[0]; l1 = l1 > 0.f ? l1 : ALPHA * l1;
        float mx = fmaxf(l0, l1);
        float e0 = expf(l0 - mx), e1 = expf(l1 - mx);
        float inv = 1.f / (e0 + e1);
        wvec[0] = e0 * inv; wvec[1] = e1 * inv;
    }
}

// ---------- GEMM2 (fp32): P[z] = (w0*att1 + w1*att2)[:, k0:k1] @ Wh[k0:k1, :] ----------
__global__ __launch_bounds__(256) void gemm2_kernel(
        const float* __restrict__ A, const float* __restrict__ A2,
        const float* __restrict__ wvec, const float* __restrict__ B,
        float* __restrict__ P, int M, int N, int K, int kchunk) {
    __shared__ __align__(16) float As[BK][LDA_];
    __shared__ __align__(16) float Bs[BK][BN];
    const int tid  = threadIdx.x;
    const int brow = blockIdx.y * BM;
    const int bcol = blockIdx.x * BN;
    const int k0   = blockIdx.z * kchunk;
    const int ar = tid >> 2;
    const int ak = (tid & 3) << 2;
    const int bk = tid >> 4;
    const int bn = (tid & 15) << 2;
    const int ty = tid >> 4;
    const int tx = tid & 15;
    const float w0 = wvec[0], w1 = wvec[1];
    float acc[8][4] = {};
    for (int kk = k0; kk < k0 + kchunk; kk += BK) {
#pragma unroll
        for (int half = 0; half < 2; ++half) {
            const int r = ar + half * 64;
            const int grow = brow + r;
            float4 av = make_float4(0.f, 0.f, 0.f, 0.f);
            if (grow < M) {
                av = *(const float4*)(A + (size_t)grow * K + kk + ak);
                float4 v2 = *(const float4*)(A2 + (size_t)grow * K + kk + ak);
                av.x = w0 * av.x + w1 * v2.x;
                av.y = w0 * av.y + w1 * v2.y;
                av.z = w0 * av.z + w1 * v2.z;
                av.w = w0 * av.w + w1 * v2.w;
            }
            As[ak + 0][r] = av.x;
            As[ak + 1][r] = av.y;
            As[ak + 2][r] = av.z;
            As[ak + 3][r] = av.w;
        }
        *(float4*)&Bs[bk][bn] = *(const float4*)(B + (size_t)(kk + bk) * N + bcol + bn);
        __syncthreads();
#pragma unroll
        for (int k = 0; k < BK; ++k) {
            float4 a0 = *(float4*)&As[k][ty * 8];
            float4 a1 = *(float4*)&As[k][ty * 8 + 4];
            float4 b  = *(float4*)&Bs[k][tx << 2];
            acc[0][0] += a0.x * b.x; acc[0][1] += a0.x * b.y; acc[0][2] += a0.x * b.z; acc[0][3] += a0.x * b.w;
            acc[1][0] += a0.y * b.x; acc[1][1] += a0.y * b.y; acc[1][2] += a0.y * b.z; acc[1][3] += a0.y * b.w;
            acc[2][0] += a0.z * b.x; acc[2][1] += a0.z * b.y; acc[2][2] += a0.z * b.z; acc[2][3] += a0.z * b.w;
            acc[3][0] += a0.w * b.x; acc[3][1] += a0.w * b.y; acc[3][2] += a0.w * b.z; acc[3][3] += a0.w * b.w;
            acc[4][0] += a1.x * b.x; acc[4][1] += a1.x * b.y; acc[4][2] += a1.x * b.z; acc[4][3] += a1.x * b.w;
            acc[5][0] += a1.y * b.x; acc[5][1] += a1.y * b.y; acc[5][2] += a1.y * b.z; acc[5][3] += a1.y * b.w;
            acc[6][0] += a1.z * b.x; acc[6][1] += a1.z * b.y; acc[6][2] += a1.z * b.z; acc[6][3] += a1.z * b.w;
            acc[7][0] += a1.w * b.x; acc[7][1] += a1.w * b.y; acc[7][2] += a1.w * b.z; acc[7][3] += a1.w * b.w;
        }
        __syncthreads();
    }
    float* Pout = P + (size_t)blockIdx.z * M * N;
#pragma unroll
    for (int ii = 0; ii < 8; ++ii) {
        const int row = brow + ty * 8 + ii;
        if (row < M)
            *(float4*)(Pout + (size_t)row * N + bcol + (tx << 2)) =
                make_float4(acc[ii][0], acc[ii][1], acc[ii][2], acc[ii][3]);
    }
}

// ---------- reduce 9 split-K partials + ELU -> out ----------
__global__ __launch_bounds__(256) void reduce9_elu_kernel(const float* __restrict__ P,
                                                          float* __restrict__ out) {
    const size_t stride = (size_t)NN * OUTF;
    size_t idx = ((size_t)blockIdx.x * 256 + threadIdx.x) * 4;
    float4 r = *(const float4*)(P + idx);
#pragma unroll
    for (int z = 1; z < KSPLIT2; ++z) {
        float4 v = *(const float4*)(P + z * stride + idx);
        r.x += v.x; r.y += v.y; r.z += v.z; r.w += v.w;
    }
    float o[4] = {r.x, r.y, r.z, r.w};
#pragma unroll
    for (int k = 0; k < 4; ++k) o[k] = o[k] > 0.f ? o[k] : expm1f(o[k]);
    *(float4*)(out + idx) = make_float4(o[0], o[1], o[2], o[3]);
}

extern "C" void kernel_launch(void* const* d_in, const int* in_sizes, int n_in,
                              void* d_out, int out_size, void* d_ws, size_t ws_size,
                              hipStream_t stream) {
    const float* h    = (const float*)d_in[0];
    // d_in[1] = adj (unused by the reference computation)
    const int*   adj1 = (const int*)d_in[2];
    const int*   adj2 = (const int*)d_in[3];
    const float* W    = (const float*)d_in[4];
    const float* a    = (const float*)d_in[5];
    const float* L_w  = (const float*)d_in[6];
    const float* L_b  = (const float*)d_in[7];
    float* out = (float*)d_out;

    // workspace layout (floats; 16B-aligned segments first)
    float* ws   = (float*)d_ws;
    const size_t PS = (size_t)NN * OUTF;                 // 884736
    float* P    = ws;                                    // 9 slices (gemm1 uses 8, gemm2 uses 9)
    float* Wh   = P + 9 * PS;
    float* att1 = Wh + PS;
    float* att2 = att1 + (size_t)NN * NN;
    float* Wa1  = att2 + (size_t)NN * NN;
    float* Wa2  = Wa1 + INF_;
    unsigned short* hbf  = (unsigned short*)(Wa2 + INF_);          // [896][4096]
    unsigned short* wtbf = hbf + (size_t)896 * INF_;               // [1024][4096]
    float* Wh1    = (float*)(wtbf + (size_t)OUTF * INF_);
    float* Wh2    = Wh1 + NN;
    float* pooled = Wh2 + NN;
    float* wvec   = pooled + 5832;

    convert_h_kernel<<<1792, 256, 0, stream>>>(h, hbf);
    transpose_w_kernel<<<dim3(4, 512), 256, 0, stream>>>(W, wtbf);
    wa_kernel<<<INF_, 256, 0, stream>>>(W, a, Wa1, Wa2);

    gemm1_mfma_kernel<<<dim3(8, 7, KSPLIT1), 256, 0, stream>>>(hbf, wtbf, P, INF_ / KSPLIT1);
    reduce8_kernel<<<NN, 256, 0, stream>>>(P, Wh);

    wh12_kernel<<<NN, 256, 0, stream>>>(h, Wa1, Wa2, Wh1, Wh2);
    attn_kernel<<<NN, 256, 0, stream>>>(Wh1, Wh2, adj1, adj2, att1, att2);
    pool_kernel<<<dim3(54, 54, 2), 256, 0, stream>>>(att1, att2, pooled);
    weights_kernel<<<1, 256, 0, stream>>>(pooled, L_w, L_b, wvec);

    gemm2_kernel<<<dim3(OUTF / BN, 7, KSPLIT2), 256, 0, stream>>>(
        att1, att2, wvec, Wh, P, NN, OUTF, NN, NN / KSPLIT2);
    reduce9_elu_kernel<<<NN, 256, 0, stream>>>(P, out);
}

// Round 4
// 175.276 us; speedup vs baseline: 1.6134x; 1.0370x over previous
//
#include <hip/hip_runtime.h>
#include <math.h>

#define NN 864
#define INF_ 4096
#define OUTF 1024
#define ALPHA 0.2f
#define NEGINF -9e15f
#define KSPLIT1 8
#define KSPLIT2 3

typedef short bf16x8 __attribute__((ext_vector_type(8)));
typedef float f32x4 __attribute__((ext_vector_type(4)));
typedef unsigned short u16x8 __attribute__((ext_vector_type(8)));

__device__ __forceinline__ unsigned short f2bf(float f) {  // round-to-nearest-even
    unsigned int u = __float_as_uint(f);
    unsigned int r = (u + 0x7fffu + ((u >> 16) & 1u)) >> 16;
    return (unsigned short)r;
}
__device__ __forceinline__ float bf2f(unsigned short u) {
    return __uint_as_float((unsigned int)u << 16);
}

// ---------- block-wide reduction of two values (256 threads = 4 waves) ----------
__device__ __forceinline__ float2 blockReduce2(float v1, float v2, bool is_max) {
    __shared__ float r1[4], r2[4];
    const int lane = threadIdx.x & 63;
    const int wid  = threadIdx.x >> 6;
#pragma unroll
    for (int o = 32; o; o >>= 1) {
        float o1 = __shfl_down(v1, o, 64);
        float o2 = __shfl_down(v2, o, 64);
        if (is_max) { v1 = fmaxf(v1, o1); v2 = fmaxf(v2, o2); }
        else        { v1 += o1;           v2 += o2; }
    }
    __syncthreads();
    if (lane == 0) { r1[wid] = v1; r2[wid] = v2; }
    __syncthreads();
    float a = r1[0], b = r2[0];
#pragma unroll
    for (int w = 1; w < 4; ++w) {
        if (is_max) { a = fmaxf(a, r1[w]); b = fmaxf(b, r2[w]); }
        else        { a += r1[w];          b += r2[w]; }
    }
    return make_float2(a, b);
}

// ---------- fused prep: h->bf16 (padded 896 rows) | W->W^T bf16 | Wa1/Wa2 fp32 ----------
__global__ __launch_bounds__(256) void prep_kernel(
        const float* __restrict__ h, const float* __restrict__ W,
        const float* __restrict__ a,
        unsigned short* __restrict__ hbf, unsigned short* __restrict__ wtbf,
        float* __restrict__ wa1, float* __restrict__ wa2) {
    const int b = blockIdx.x;
    if (b < 1792) {                        // convert h: 896*4096/8 elems per thread-8
        const int i = b * 256 + threadIdx.x;
        const size_t base = (size_t)i * 8;
        const int row = (int)(base >> 12);
        u16x8 o;
        if (row < NN) {
            float4 f0 = *(const float4*)(h + base);
            float4 f1 = *(const float4*)(h + base + 4);
            o[0] = f2bf(f0.x); o[1] = f2bf(f0.y); o[2] = f2bf(f0.z); o[3] = f2bf(f0.w);
            o[4] = f2bf(f1.x); o[5] = f2bf(f1.y); o[6] = f2bf(f1.z); o[7] = f2bf(f1.w);
        } else {
#pragma unroll
            for (int j = 0; j < 8; ++j) o[j] = 0;
        }
        *(u16x8*)(hbf + base) = o;
    } else if (b < 3840) {                 // W^T bf16
        const int b2 = b - 1792;
        const int n  = (b2 & 3) * 256 + threadIdx.x;
        const int k0 = (b2 >> 2) * 8;
        u16x8 o;
#pragma unroll
        for (int j = 0; j < 8; ++j) o[j] = f2bf(W[(size_t)(k0 + j) * OUTF + n]);
        *(u16x8*)(wtbf + (size_t)n * INF_ + k0) = o;
    } else {                               // Wa1/Wa2 (fp32 exact logits path)
        const int k = b - 3840;
        const float* row = W + (size_t)k * OUTF;
        const int f = threadIdx.x << 2;
        float4 w = *(const float4*)(row + f);
        float4 x = *(const float4*)(a + f);
        float4 y = *(const float4*)(a + OUTF + f);
        float s1 = w.x * x.x + w.y * x.y + w.z * x.z + w.w * x.w;
        float s2 = w.x * y.x + w.y * y.y + w.z * y.z + w.w * y.w;
        float2 s = blockReduce2(s1, s2, false);
        if (threadIdx.x == 0) { wa1[k] = s.x; wa2[k] = s.y; }
    }
}

// ---------- Wh1 = h@Wa1, Wh2 = h@Wa2 (fp32, one block per row) ----------
__global__ __launch_bounds__(256) void wh12_kernel(const float* __restrict__ h,
                                                   const float* __restrict__ wa1,
                                                   const float* __restrict__ wa2,
                                                   float* __restrict__ wh1,
                                                   float* __restrict__ wh2) {
    const int i = blockIdx.x;
    const float* row = h + (size_t)i * INF_;
    float s1 = 0.f, s2 = 0.f;
    for (int f = threadIdx.x << 2; f < INF_; f += 1024) {
        float4 hv = *(const float4*)(row + f);
        float4 x  = *(const float4*)(wa1 + f);
        float4 y  = *(const float4*)(wa2 + f);
        s1 += hv.x * x.x + hv.y * x.y + hv.z * x.z + hv.w * x.w;
        s2 += hv.x * y.x + hv.y * y.y + hv.z * y.z + hv.w * y.w;
    }
    float2 s = blockReduce2(s1, s2, false);
    if (threadIdx.x == 0) { wh1[i] = s.x; wh2[i] = s.y; }
}

// ---------- GEMM1 (bf16 MFMA): P[z] = hbf @ wtbf^T, 128x128 tile, BK=32 ----------
__global__ __launch_bounds__(256) void gemm1_mfma_kernel(
        const unsigned short* __restrict__ Abf,   // [896][4096]
        const unsigned short* __restrict__ Btbf,  // [1024][4096]
        float* __restrict__ P, int kchunk) {
    __shared__ unsigned short Als[128][40];
    __shared__ unsigned short Bls[128][40];
    const int tid  = threadIdx.x;
    const int lane = tid & 63;
    const int wid  = tid >> 6;
    const int wr   = (wid >> 1) * 64;
    const int wc   = (wid & 1) * 64;
    const int brow = blockIdx.y * 128;
    const int bcol = blockIdx.x * 128;
    const int k0   = blockIdx.z * kchunk;
    const int r0   = tid >> 2;
    const int kq0  = (tid & 3) << 3;

    f32x4 acc[4][4];
#pragma unroll
    for (int m = 0; m < 4; ++m)
#pragma unroll
        for (int n = 0; n < 4; ++n) acc[m][n] = (f32x4){0.f, 0.f, 0.f, 0.f};

    const unsigned short* ag = Abf  + (size_t)(brow + r0) * INF_ + kq0;
    const unsigned short* bg = Btbf + (size_t)(bcol + r0) * INF_ + kq0;
    const int rl  = lane & 15;
    const int kq2 = (lane >> 4) << 3;

    for (int kk = k0; kk < k0 + kchunk; kk += 32) {
        bf16x8 a0 = *(const bf16x8*)(ag + kk);
        bf16x8 a1 = *(const bf16x8*)(ag + (size_t)64 * INF_ + kk);
        bf16x8 b0 = *(const bf16x8*)(bg + kk);
        bf16x8 b1 = *(const bf16x8*)(bg + (size_t)64 * INF_ + kk);
        __syncthreads();
        *(bf16x8*)&Als[r0][kq0]      = a0;
        *(bf16x8*)&Als[r0 + 64][kq0] = a1;
        *(bf16x8*)&Bls[r0][kq0]      = b0;
        *(bf16x8*)&Bls[r0 + 64][kq0] = b1;
        __syncthreads();
        bf16x8 af[4], bfr[4];
#pragma unroll
        for (int m = 0; m < 4; ++m) af[m]  = *(const bf16x8*)&Als[wr + m * 16 + rl][kq2];
#pragma unroll
        for (int n = 0; n < 4; ++n) bfr[n] = *(const bf16x8*)&Bls[wc + n * 16 + rl][kq2];
#pragma unroll
        for (int m = 0; m < 4; ++m)
#pragma unroll
            for (int n = 0; n < 4; ++n)
                acc[m][n] = __builtin_amdgcn_mfma_f32_16x16x32_bf16(af[m], bfr[n], acc[m][n], 0, 0, 0);
    }

    float* Pz = P + (size_t)blockIdx.z * NN * OUTF;
    const int rg = (lane >> 4) << 2;   // C/D: col=lane&15, row=(lane>>4)*4+reg (m89)
#pragma unroll
    for (int m = 0; m < 4; ++m) {
#pragma unroll
        for (int n = 0; n < 4; ++n) {
            const int row0 = brow + wr + m * 16 + rg;
            const int col  = bcol + wc + n * 16 + rl;
#pragma unroll
            for (int reg = 0; reg < 4; ++reg) {
                const int row = row0 + reg;
                if (row < NN) Pz[(size_t)row * OUTF + col] = acc[m][n][reg];
            }
        }
    }
}

// ---------- reduce 8 split-K partials -> Wh^T bf16 [1024][864] ----------
__global__ __launch_bounds__(256) void reduce8t_kernel(const float* __restrict__ P,
                                                       unsigned short* __restrict__ Wt) {
    const int m  = blockIdx.x;             // row of Wh
    const int c0 = threadIdx.x * 4;        // 4 consecutive cols
    const size_t stride = (size_t)NN * OUTF;
    const float* base = P + (size_t)m * OUTF + c0;
    float4 r = *(const float4*)base;
#pragma unroll
    for (int z = 1; z < KSPLIT1; ++z) {
        float4 v = *(const float4*)(base + (size_t)z * stride);
        r.x += v.x; r.y += v.y; r.z += v.z; r.w += v.w;
    }
    Wt[(size_t)(c0 + 0) * NN + m] = f2bf(r.x);
    Wt[(size_t)(c0 + 1) * NN + m] = f2bf(r.y);
    Wt[(size_t)(c0 + 2) * NN + m] = f2bf(r.z);
    Wt[(size_t)(c0 + 3) * NN + m] = f2bf(r.w);
}

// ---------- attention row: 2 masked softmaxes -> att bf16 + 16-col pool partials ----------
__global__ __launch_bounds__(256) void attn_kernel(
        const float* __restrict__ Wh1, const float* __restrict__ Wh2,
        const int* __restrict__ adj1, const int* __restrict__ adj2,
        unsigned short* __restrict__ att1, unsigned short* __restrict__ att2,
        float* __restrict__ rowpool) {
    const int i   = blockIdx.x;
    const int tid = threadIdx.x;
    const float wh1 = Wh1[i];
    float l1v[4], l2v[4], x1v[4], x2v[4];
    float m1 = NEGINF, m2 = NEGINF;
    int cnt = 0;
    for (int c = tid; c < NN; c += 256, ++cnt) {
        float e = wh1 + Wh2[c];
        e = e > 0.f ? e : ALPHA * e;
        float l1 = adj1[(size_t)i * NN + c] > 0 ? e : NEGINF;
        float l2 = adj2[(size_t)i * NN + c] > 0 ? e : NEGINF;
        l1v[cnt] = l1; l2v[cnt] = l2;
        m1 = fmaxf(m1, l1); m2 = fmaxf(m2, l2);
    }
    float2 m = blockReduce2(m1, m2, true);
    float s1 = 0.f, s2 = 0.f;
    cnt = 0;
    for (int c = tid; c < NN; c += 256, ++cnt) {
        float x1 = expf(l1v[cnt] - m.x);   // masked -> underflow to 0, matches JAX
        float x2 = expf(l2v[cnt] - m.y);
        x1v[cnt] = x1; x2v[cnt] = x2;
        s1 += x1; s2 += x2;
    }
    float2 s = blockReduce2(s1, s2, false);
    const float inv1 = 1.f / s.x, inv2 = 1.f / s.y;
    cnt = 0;
#pragma unroll
    for (int ch = 0; ch < 4; ++ch) {       // all lanes participate (shfl safety)
        const int c = tid + ch * 256;
        const bool valid = c < NN;
        float a1 = NEGINF, a2 = NEGINF;
        if (valid) {
            a1 = x1v[cnt] * inv1;
            a2 = x2v[cnt] * inv2;
            att1[(size_t)i * NN + c] = f2bf(a1);
            att2[(size_t)i * NN + c] = f2bf(a2);
            ++cnt;
        }
#pragma unroll
        for (int off = 8; off; off >>= 1) {   // max within 16-lane group (one pj)
            a1 = fmaxf(a1, __shfl_xor(a1, off, 64));
            a2 = fmaxf(a2, __shfl_xor(a2, off, 64));
        }
        const int pj = (tid >> 4) + ch * 16;
        if ((tid & 15) == 0 && pj < 54) {
            rowpool[(size_t)i * 54 + pj] = a1;
            rowpool[(size_t)NN * 54 + (size_t)i * 54 + pj] = a2;
        }
    }
}

// ---------- finish pool over 16 rows + linear + leaky + softmax -> wvec ----------
__global__ __launch_bounds__(1024) void poolw_kernel(const float* __restrict__ rowpool,
                                                     const float* __restrict__ L_w,
                                                     const float* __restrict__ L_b,
                                                     float* __restrict__ wvec) {
    __shared__ float r1[16], r2[16];
    const int t = threadIdx.x;
    float p0 = 0.f, p1 = 0.f;
    for (int p = t; p < 2916; p += 1024) {
        const int pi = p / 54, pj = p - pi * 54;
        const float* rp0 = rowpool + (size_t)(pi * 16) * 54 + pj;
        const float* rp1 = rp0 + (size_t)NN * 54;
        float mx0 = NEGINF, mx1 = NEGINF;
#pragma unroll
        for (int r = 0; r < 16; ++r) {
            mx0 = fmaxf(mx0, rp0[r * 54]);
            mx1 = fmaxf(mx1, rp1[r * 54]);
        }
        const float lw = L_w[p];
        p0 += mx0 * lw; p1 += mx1 * lw;
    }
#pragma unroll
    for (int o = 32; o; o >>= 1) { p0 += __shfl_down(p0, o, 64); p1 += __shfl_down(p1, o, 64); }
    if ((t & 63) == 0) { r1[t >> 6] = p0; r2[t >> 6] = p1; }
    __syncthreads();
    if (t == 0) {
        float s0 = 0.f, s1 = 0.f;
#pragma unroll
        for (int w = 0; w < 16; ++w) { s0 += r1[w]; s1 += r2[w]; }
        float l0 = s0 + L_b[0]; l0 = l0 > 0.f ? l0 : ALPHA * l0;
        float l1 = s1 + L_b[0]; l1 = l1 > 0.f ? l1 : ALPHA * l1;
        const float mx = fmaxf(l0, l1);
        const float e0 = expf(l0 - mx), e1 = expf(l1 - mx);
        const float inv = 1.f / (e0 + e1);
        wvec[0] = e0 * inv; wvec[1] = e1 * inv;
    }
}

// ---------- GEMM2 (bf16 MFMA): P[z] = bf16(w0*att1+w1*att2) @ Wh, K=864 ----------
__global__ __launch_bounds__(256) void gemm2_mfma_kernel(
        const unsigned short* __restrict__ A1, const unsigned short* __restrict__ A2,
        const float* __restrict__ wvec, const unsigned short* __restrict__ Bt,  // [1024][864]
        float* __restrict__ P, int kchunk) {
    __shared__ unsigned short Als[128][40];
    __shared__ unsigned short Bls[128][40];
    const int tid  = threadIdx.x;
    const int lane = tid & 63;
    const int wid  = tid >> 6;
    const int wr   = (wid >> 1) * 64;
    const int wc   = (wid & 1) * 64;
    const int brow = blockIdx.y * 128;
    const int bcol = blockIdx.x * 128;
    const int k0   = blockIdx.z * kchunk;
    const int r0   = tid >> 2;
    const int kq0  = (tid & 3) << 3;
    const float w0 = wvec[0], w1 = wvec[1];

    f32x4 acc[4][4];
#pragma unroll
    for (int m = 0; m < 4; ++m)
#pragma unroll
        for (int n = 0; n < 4; ++n) acc[m][n] = (f32x4){0.f, 0.f, 0.f, 0.f};

    const int rl  = lane & 15;
    const int kq2 = (lane >> 4) << 3;

    for (int kk = k0; kk < k0 + kchunk; kk += 32) {
        u16x8 av[2];
#pragma unroll
        for (int half = 0; half < 2; ++half) {
            const int grow = brow + r0 + half * 64;
            u16x8 o;
            if (grow < NN) {
                u16x8 v1 = *(const u16x8*)(A1 + (size_t)grow * NN + kk + kq0);
                u16x8 v2 = *(const u16x8*)(A2 + (size_t)grow * NN + kk + kq0);
#pragma unroll
                for (int j = 0; j < 8; ++j)
                    o[j] = f2bf(w0 * bf2f(v1[j]) + w1 * bf2f(v2[j]));
            } else {
#pragma unroll
                for (int j = 0; j < 8; ++j) o[j] = 0;
            }
            av[half] = o;
        }
        u16x8 b0 = *(const u16x8*)(Bt + (size_t)(bcol + r0) * NN + kk + kq0);
        u16x8 b1 = *(const u16x8*)(Bt + (size_t)(bcol + r0 + 64) * NN + kk + kq0);
        __syncthreads();
        *(u16x8*)&Als[r0][kq0]      = av[0];
        *(u16x8*)&Als[r0 + 64][kq0] = av[1];
        *(u16x8*)&Bls[r0][kq0]      = b0;
        *(u16x8*)&Bls[r0 + 64][kq0] = b1;
        __syncthreads();
        bf16x8 af[4], bfr[4];
#pragma unroll
        for (int m = 0; m < 4; ++m) af[m]  = *(const bf16x8*)&Als[wr + m * 16 + rl][kq2];
#pragma unroll
        for (int n = 0; n < 4; ++n) bfr[n] = *(const bf16x8*)&Bls[wc + n * 16 + rl][kq2];
#pragma unroll
        for (int m = 0; m < 4; ++m)
#pragma unroll
            for (int n = 0; n < 4; ++n)
                acc[m][n] = __builtin_amdgcn_mfma_f32_16x16x32_bf16(af[m], bfr[n], acc[m][n], 0, 0, 0);
    }

    float* Pz = P + (size_t)blockIdx.z * NN * OUTF;
    const int rg = (lane >> 4) << 2;
#pragma unroll
    for (int m = 0; m < 4; ++m) {
#pragma unroll
        for (int n = 0; n < 4; ++n) {
            const int row0 = brow + wr + m * 16 + rg;
            const int col  = bcol + wc + n * 16 + rl;
#pragma unroll
            for (int reg = 0; reg < 4; ++reg) {
                const int row = row0 + reg;
                if (row < NN) Pz[(size_t)row * OUTF + col] = acc[m][n][reg];
            }
        }
    }
}

// ---------- reduce 3 split-K partials + ELU -> out ----------
__global__ __launch_bounds__(256) void reduce3_elu_kernel(const float* __restrict__ P,
                                                          float* __restrict__ out) {
    const size_t stride = (size_t)NN * OUTF;
    size_t idx = ((size_t)blockIdx.x * 256 + threadIdx.x) * 4;
    float4 r = *(const float4*)(P + idx);
#pragma unroll
    for (int z = 1; z < KSPLIT2; ++z) {
        float4 v = *(const float4*)(P + z * stride + idx);
        r.x += v.x; r.y += v.y; r.z += v.z; r.w += v.w;
    }
    float o[4] = {r.x, r.y, r.z, r.w};
#pragma unroll
    for (int k = 0; k < 4; ++k) o[k] = o[k] > 0.f ? o[k] : expm1f(o[k]);
    *(float4*)(out + idx) = make_float4(o[0], o[1], o[2], o[3]);
}

extern "C" void kernel_launch(void* const* d_in, const int* in_sizes, int n_in,
                              void* d_out, int out_size, void* d_ws, size_t ws_size,
                              hipStream_t stream) {
    const float* h    = (const float*)d_in[0];
    // d_in[1] = adj (unused by the reference computation)
    const int*   adj1 = (const int*)d_in[2];
    const int*   adj2 = (const int*)d_in[3];
    const float* W    = (const float*)d_in[4];
    const float* a    = (const float*)d_in[5];
    const float* L_w  = (const float*)d_in[6];
    const float* L_b  = (const float*)d_in[7];
    float* out = (float*)d_out;

    float* ws = (float*)d_ws;
    const size_t PS = (size_t)NN * OUTF;            // 884736
    float* P       = ws;                            // 8 slices (gemm2 reuses 0..2)
    float* Wa1     = P + 8 * PS;
    float* Wa2     = Wa1 + INF_;
    float* Wh1     = Wa2 + INF_;
    float* Wh2     = Wh1 + NN;
    float* rowpool = Wh2 + NN;                      // 2*864*54
    float* wvec    = rowpool + 2 * NN * 54;         // 2 (pad 4)
    unsigned short* hbf    = (unsigned short*)(wvec + 4);          // [896][4096]
    unsigned short* wtbf   = hbf + (size_t)896 * INF_;             // [1024][4096]
    unsigned short* Whbf_t = wtbf + (size_t)OUTF * INF_;           // [1024][864]
    unsigned short* att1bf = Whbf_t + (size_t)OUTF * NN;           // [864][864]
    unsigned short* att2bf = att1bf + (size_t)NN * NN;             // [864][864]

    prep_kernel<<<7936, 256, 0, stream>>>(h, W, a, hbf, wtbf, Wa1, Wa2);
    wh12_kernel<<<NN, 256, 0, stream>>>(h, Wa1, Wa2, Wh1, Wh2);
    gemm1_mfma_kernel<<<dim3(8, 7, KSPLIT1), 256, 0, stream>>>(hbf, wtbf, P, INF_ / KSPLIT1);
    reduce8t_kernel<<<NN, 256, 0, stream>>>(P, Whbf_t);
    attn_kernel<<<NN, 256, 0, stream>>>(Wh1, Wh2, adj1, adj2, att1bf, att2bf, rowpool);
    poolw_kernel<<<1, 1024, 0, stream>>>(rowpool, L_w, L_b, wvec);
    gemm2_mfma_kernel<<<dim3(8, 7, KSPLIT2), 256, 0, stream>>>(att1bf, att2bf, wvec, Whbf_t, P, NN / KSPLIT2);
    reduce3_elu_kernel<<<NN, 256, 0, stream>>>(P, out);
}